// Round 6
// baseline (339.134 us; speedup 1.0000x reference)
//
#include <hip/hip_runtime.h>

// ODEDriftIntegrator: 24 RHS evals of a 2->64->64->1 tanh MLP per point,
// Dormand-Prince fixed-step (k7 dead: b7=0). Wave = 16 points via
// mfma_f32_16x16x32_f16 computing W2^T @ H1^T (point index == lane&15 for
// B-operand and D-output; A/B k-convention self-consistent).
//
// R6: all f16 math as explicit inline-asm VOP3P (v_pk_fma/mul/max/min_f16) --
// R4/R5 counters showed ~2.5x more issued VALU than the packed-source model
// (suspected scalarization + VOP3P-literal rematerialization). tanh poly
// constants are replicated-half SGPR immediates ("s" operands; one per
// instr; replication makes op_sel irrelevant). Same validated quartic math
// as R4 (absmax floor 0.0078): tanh(s), t=s/2 pre-folded into W1/W2/b2:
// y = t*q(t^2), clamp |t|<=1.55.

typedef __attribute__((ext_vector_type(2))) __fp16 h2;
typedef __attribute__((ext_vector_type(8))) __fp16 h8;
typedef __attribute__((ext_vector_type(4))) float f32x4;

#define NPTS   (131072 * 5)
#define NBATCH (NPTS / 16)          // 40960 batches of 16 points

// packed-half constants (both halves identical)
#define Q0C 0x3FE73FE7u  //  1.9756
#define Q1C 0xC038C038u  // -2.1094
#define Q2C 0x3E933E93u  //  1.6436
#define Q3C 0xB933B933u  // -0.6499
#define Q4C 0x2E472E47u  //  0.0981
#define LPC 0x3E333E33u  //  1.5498
#define LNC 0xBE33BE33u  // -1.5498

__device__ __forceinline__ unsigned u_of(h2 x) { return __builtin_bit_cast(unsigned, x); }
__device__ __forceinline__ h2 h_of(unsigned x) { return __builtin_bit_cast(h2, x); }
__device__ __forceinline__ unsigned pkrtz_u(float a, float b) {
  return u_of(__builtin_amdgcn_cvt_pkrtz(a, b));
}
__device__ __forceinline__ unsigned pk_fma_vvv(unsigned a, unsigned b, unsigned c) {
  unsigned d; asm("v_pk_fma_f16 %0, %1, %2, %3" : "=v"(d) : "v"(a), "v"(b), "v"(c)); return d;
}
__device__ __forceinline__ unsigned pk_fma_vvs(unsigned a, unsigned b, unsigned cs) {
  unsigned d; asm("v_pk_fma_f16 %0, %1, %2, %3" : "=v"(d) : "v"(a), "v"(b), "s"(cs)); return d;
}
__device__ __forceinline__ unsigned pk_mul_vv(unsigned a, unsigned b) {
  unsigned d; asm("v_pk_mul_f16 %0, %1, %2" : "=v"(d) : "v"(a), "v"(b)); return d;
}
__device__ __forceinline__ unsigned pk_max_vs(unsigned a, unsigned bs) {
  unsigned d; asm("v_pk_max_f16 %0, %1, %2" : "=v"(d) : "v"(a), "s"(bs)); return d;
}
__device__ __forceinline__ unsigned pk_min_vs(unsigned a, unsigned bs) {
  unsigned d; asm("v_pk_min_f16 %0, %1, %2" : "=v"(d) : "v"(a), "s"(bs)); return d;
}
// tanh with pre-halved arg: 8 guaranteed-packed ops, SGPR consts (no remat).
__device__ __forceinline__ unsigned tanh_pku(unsigned sh, unsigned q4v) {
  unsigned s = pk_max_vs(sh, LNC);
  s = pk_min_vs(s, LPC);
  unsigned w = pk_mul_vv(s, s);
  unsigned p = pk_fma_vvs(q4v, w, Q3C);
  p = pk_fma_vvs(p, w, Q2C);
  p = pk_fma_vvs(p, w, Q1C);
  p = pk_fma_vvs(p, w, Q0C);
  return pk_mul_vv(s, p);
}

union HU { unsigned u[4]; h8 v; };

__global__ __launch_bounds__(256, 4) void ode_mfma_kernel(
    const float* __restrict__ sigmap,  // [NPTS,3]
    const float* __restrict__ Wpp,     // [NPTS]
    const float* __restrict__ W1p,     // [2,64]
    const float* __restrict__ b1p,     // [64]
    const float* __restrict__ W2p,     // [64,64]
    const float* __restrict__ b2p,     // [64]
    const float* __restrict__ W3p,     // [64,1]
    const float* __restrict__ b3p,     // [1]
    float* __restrict__ outp)          // [131072]
{
  const int lane = threadIdx.x & 63;
  const int col  = lane & 15;   // point slot within batch (B-col == D-col)
  const int g    = lane >> 4;   // lane group (k-group / D-row group)
  const int wid  = blockIdx.x * (blockDim.x >> 6) + (threadIdx.x >> 6);
  const int nw   = gridDim.x * (blockDim.x >> 6);

  // Q4 pinned in a VGPR once (opaque asm: loop-hoisted, cannot rematerialize)
  unsigned q4v; asm("v_mov_b32 %0, 0x2E472E47" : "=v"(q4v));

  // ---- persistent per-lane constants ----
  // layer1: packed pair ee: ee<4 -> j0=8g+2ee (k-frag 0); ee>=4 -> 32+8g+2(ee-4).
  unsigned w10u[8];
#pragma unroll
  for (int ee = 0; ee < 8; ++ee) {
    int j0 = (ee < 4) ? (8 * g + 2 * ee) : (32 + 8 * g + 2 * (ee - 4));
    w10u[ee] = pkrtz_u(0.5f * W1p[j0], 0.5f * W1p[j0 + 1]);
  }
  // A-frags = 0.5*W2^T (f16). tile t = out-hidden [16t,16t+16); A-row = col;
  // k element e at group g -> in-hidden kt*32 + 8g + e.
  HU afr[4][2];
#pragma unroll
  for (int t = 0; t < 4; ++t)
#pragma unroll
    for (int kt = 0; kt < 2; ++kt)
#pragma unroll
      for (int ee = 0; ee < 4; ++ee) {
        int k0 = kt * 32 + 8 * g + 2 * ee;
        afr[t][kt].u[ee] = pkrtz_u(0.5f * W2p[(k0)     * 64 + 16 * t + col],
                                   0.5f * W2p[(k0 + 1) * 64 + 16 * t + col]);
      }
  // D-side: lane holds out-hidden j = 16t + 4g + r. Bias (x0.5) as MFMA C-init.
  f32x4 cinit[4];
  unsigned w3u[8];
#pragma unroll
  for (int t = 0; t < 4; ++t) {
    int jb = 16 * t + 4 * g;
#pragma unroll
    for (int r = 0; r < 4; ++r) cinit[t][r] = 0.5f * b2p[jb + r];
    w3u[2 * t]     = pkrtz_u(W3p[jb],     W3p[jb + 1]);
    w3u[2 * t + 1] = pkrtz_u(W3p[jb + 2], W3p[jb + 3]);
  }
  const float b3v = b3p[0];

  // DP coefficients (h pre-multiplied)
  const float h   = 0.0025f;
  const float c21 = h * (1.0f / 5.0f);
  const float c31 = h * (3.0f / 40.0f),      c32 = h * (9.0f / 40.0f);
  const float c41 = h * (44.0f / 45.0f),     c42 = -h * (56.0f / 15.0f),    c43 = h * (32.0f / 9.0f);
  const float c51 = h * (19372.0f / 6561.0f), c52 = -h * (25360.0f / 2187.0f),
              c53 = h * (64448.0f / 6561.0f), c54 = -h * (212.0f / 729.0f);
  const float c61 = h * (9017.0f / 3168.0f),  c62 = -h * (355.0f / 33.0f),
              c63 = h * (46732.0f / 5247.0f), c64 = h * (49.0f / 176.0f),   c65 = -h * (5103.0f / 18656.0f);
  const float d1 = h * (35.0f / 384.0f), d3 = h * (500.0f / 1113.0f), d4 = h * (125.0f / 192.0f),
              d5 = -h * (2187.0f / 6784.0f), d6 = h * (11.0f / 84.0f);

#pragma unroll 1
  for (int batch = wid; batch < NBATCH; batch += nw) {
    const int p = batch * 16 + col;
    float x           = sigmap[3 * p + 0];
    const float u     = sigmap[3 * p + 1];
    const float wdiff = sigmap[3 * p + 2];

    // cvu[ee] = 0.5*(u*W1[1][j] + b1[j]) packed (W1/b1 re-read: L1-resident)
    unsigned cvu[8];
#pragma unroll
    for (int ee = 0; ee < 8; ++ee) {
      int j0 = (ee < 4) ? (8 * g + 2 * ee) : (32 + 8 * g + 2 * (ee - 4));
      cvu[ee] = pkrtz_u(0.5f * fmaf(u, W1p[64 + j0],     b1p[j0]),
                        0.5f * fmaf(u, W1p[64 + j0 + 1], b1p[j0 + 1]));
    }

    auto rhs = [&](float xi) -> float {
      unsigned xh = pkrtz_u(xi, xi);
      // layer1: 16 tanh (8 packed calls) -> two B-frags (H1^T) in f16
      HU b0, b1f;
#pragma unroll
      for (int ee = 0; ee < 4; ++ee) {
        b0.u[ee]  = tanh_pku(pk_fma_vvv(xh, w10u[ee],     cvu[ee]),     q4v);
        b1f.u[ee] = tanh_pku(pk_fma_vvv(xh, w10u[ee + 4], cvu[ee + 4]), q4v);
      }
      // layer2 (MFMA, bias in C-init) + epilogue tanh + layer3 packed dot
      unsigned ph = 0;
#pragma unroll
      for (int t = 0; t < 4; ++t) {
        f32x4 acc = cinit[t];
        acc = __builtin_amdgcn_mfma_f32_16x16x32_f16(afr[t][0].v, b0.v,  acc, 0, 0, 0);
        acc = __builtin_amdgcn_mfma_f32_16x16x32_f16(afr[t][1].v, b1f.v, acc, 0, 0, 0);
        unsigned th0 = tanh_pku(pkrtz_u(acc[0], acc[1]), q4v);
        unsigned th1 = tanh_pku(pkrtz_u(acc[2], acc[3]), q4v);
        ph = pk_fma_vvv(th0, w3u[2 * t],     ph);
        ph = pk_fma_vvv(th1, w3u[2 * t + 1], ph);
      }
      h2 phh = h_of(ph);
      float partial = (float)phh[0] + (float)phh[1];
      // sum the 4 k-groups (same col, g=0..3)
      partial += __shfl_xor(partial, 16, 64);
      partial += __shfl_xor(partial, 32, 64);
      return partial + b3v;
    };

#pragma unroll 1
    for (int step = 0; step < 4; ++step) {
      float k1 = rhs(x);
      float k2 = rhs(fmaf(c21, k1, x));
      float k3 = rhs(fmaf(c32, k2, fmaf(c31, k1, x)));
      float k4 = rhs(fmaf(c43, k3, fmaf(c42, k2, fmaf(c41, k1, x))));
      float k5 = rhs(fmaf(c54, k4, fmaf(c53, k3, fmaf(c52, k2, fmaf(c51, k1, x)))));
      float k6 = rhs(fmaf(c65, k5, fmaf(c64, k4, fmaf(c63, k3, fmaf(c62, k2, fmaf(c61, k1, x))))));
      x = fmaf(d6, k6, fmaf(d5, k5, fmaf(d4, k4, fmaf(d3, k3, fmaf(d1, k1, x)))));
    }

    x = fmaf(0.01f, wdiff, x);  // diffusion kick: sqrt(2*0.5*sigma^2*dt) = 0.01

    if (lane < 16) {  // one replica writes
      atomicAdd(&outp[p / 5], Wpp[p] * x);
    }
  }
}

extern "C" void kernel_launch(void* const* d_in, const int* in_sizes, int n_in,
                              void* d_out, int out_size, void* d_ws, size_t ws_size,
                              hipStream_t stream) {
  const float* sigmap = (const float*)d_in[0];
  const float* Wpp    = (const float*)d_in[1];
  const float* W1p    = (const float*)d_in[2];
  const float* b1p    = (const float*)d_in[3];
  const float* W2p    = (const float*)d_in[4];
  const float* b2p    = (const float*)d_in[5];
  const float* W3p    = (const float*)d_in[6];
  const float* b3p    = (const float*)d_in[7];
  float* outp = (float*)d_out;

  (void)hipMemsetAsync(outp, 0, (size_t)out_size * sizeof(float), stream);
  ode_mfma_kernel<<<2560, 256, 0, stream>>>(sigmap, Wpp, W1p, b1p, W2p, b2p,
                                            W3p, b3p, outp);
  (void)d_ws; (void)ws_size; (void)n_in; (void)in_sizes;
}

// Round 7
// 285.814 us; speedup vs baseline: 1.1866x; 1.1866x over previous
//
#include <hip/hip_runtime.h>

// ODEDriftIntegrator: 24 RHS evals of a 2->64->64->1 tanh MLP per point,
// Dormand-Prince fixed-step (k7 dead: b7=0). Wave = 2 batches x 16 points via
// mfma_f32_16x16x32_f16 computing W2^T @ H1^T (point index == lane&15 for
// B-operand and D-output; A/B k-convention self-consistent).
//
// R7: (1) 6-op packed tanh: y = clamp(s*(c0+c1*w+c2*w^2), +-1), w=s*s, output
// clamp only (poly diverges monotonically outside fit range; f16 inf clamps
// correctly). Fit of tanh(2t) on |t|<=1.55, max err ~0.09 -- yhat error
// contribution ~2e-3 vs 5.2e-2 threshold (drift enters output scaled by
// DT=0.01). (2) Two independent batches per wave (2 DP chains) so one
// chain's VALU hides the other's MFMA/shfl/convert latency. R4/R5/R6
// established VOP3P ~ 4cy/wave64 (f16 packed == f32 FLOP rate), issue-port
// ~94% busy -> only op-count cuts and latency amortization can help.

typedef __attribute__((ext_vector_type(2))) __fp16 h2;
typedef __attribute__((ext_vector_type(8))) __fp16 h8;
typedef __attribute__((ext_vector_type(4))) float f32x4;

#define NPTS   (131072 * 5)
#define NBATCH (NPTS / 16)          // 40960 batches of 16 points

// packed-half constants (both halves identical)
#define C0C 0x3F913F91u  //  1.8916
#define C1C 0xBD96BD96u  // -1.3965
#define C2C 0x36B036B0u  //  0.41797
#define ONEC 0x3C003C00u //  1.0
#define NEG1C 0xBC00BC00u// -1.0

__device__ __forceinline__ unsigned u_of(h2 x) { return __builtin_bit_cast(unsigned, x); }
__device__ __forceinline__ h2 h_of(unsigned x) { return __builtin_bit_cast(h2, x); }
__device__ __forceinline__ unsigned pkrtz_u(float a, float b) {
  return u_of(__builtin_amdgcn_cvt_pkrtz(a, b));
}
__device__ __forceinline__ unsigned pk_fma_vvv(unsigned a, unsigned b, unsigned c) {
  unsigned d; asm("v_pk_fma_f16 %0, %1, %2, %3" : "=v"(d) : "v"(a), "v"(b), "v"(c)); return d;
}
__device__ __forceinline__ unsigned pk_fma_vvs(unsigned a, unsigned b, unsigned cs) {
  unsigned d; asm("v_pk_fma_f16 %0, %1, %2, %3" : "=v"(d) : "v"(a), "v"(b), "s"(cs)); return d;
}
__device__ __forceinline__ unsigned pk_mul_vv(unsigned a, unsigned b) {
  unsigned d; asm("v_pk_mul_f16 %0, %1, %2" : "=v"(d) : "v"(a), "v"(b)); return d;
}
__device__ __forceinline__ unsigned pk_max_vs(unsigned a, unsigned bs) {
  unsigned d; asm("v_pk_max_f16 %0, %1, %2" : "=v"(d) : "v"(a), "s"(bs)); return d;
}
__device__ __forceinline__ unsigned pk_min_vs(unsigned a, unsigned bs) {
  unsigned d; asm("v_pk_min_f16 %0, %1, %2" : "=v"(d) : "v"(a), "s"(bs)); return d;
}
// 6-op tanh, arg pre-halved (t = s/2 folded into weights), approximates
// tanh(2t): w=t*t; p=c2*w+c1; p=p*w+c0; y=t*p; y=min(y,1); y=max(y,-1).
// c2 lives in a pinned VGPR (c2v) so each op reads at most one SGPR.
__device__ __forceinline__ unsigned tanh6(unsigned s, unsigned c2v) {
  unsigned w = pk_mul_vv(s, s);
  unsigned p = pk_fma_vvs(c2v, w, C1C);
  p = pk_fma_vvs(p, w, C0C);
  unsigned y = pk_mul_vv(s, p);
  y = pk_min_vs(y, ONEC);
  return pk_max_vs(y, NEG1C);
}

union HU { unsigned u[4]; h8 v; };

__global__ __launch_bounds__(256, 4) void ode_mfma_kernel(
    const float* __restrict__ sigmap,  // [NPTS,3]
    const float* __restrict__ Wpp,     // [NPTS]
    const float* __restrict__ W1p,     // [2,64]
    const float* __restrict__ b1p,     // [64]
    const float* __restrict__ W2p,     // [64,64]
    const float* __restrict__ b2p,     // [64]
    const float* __restrict__ W3p,     // [64,1]
    const float* __restrict__ b3p,     // [1]
    float* __restrict__ outp)          // [131072]
{
  const int lane = threadIdx.x & 63;
  const int col  = lane & 15;   // point slot within batch (B-col == D-col)
  const int g    = lane >> 4;   // lane group (k-group / D-row group)
  const int wid  = blockIdx.x * (blockDim.x >> 6) + (threadIdx.x >> 6);
  const int nw   = gridDim.x * (blockDim.x >> 6);

  // pinned VGPR for poly c2 (cannot rematerialize; 1-SGPR rule respected)
  unsigned c2v; asm("v_mov_b32 %0, 0x36B036B0" : "=v"(c2v));

  // ---- persistent per-lane constants ----
  // layer1 packed pair ee: ee<4 -> j0=8g+2ee (k-frag 0); ee>=4 -> 32+8g+2(ee-4).
  unsigned w10u[8];
#pragma unroll
  for (int ee = 0; ee < 8; ++ee) {
    int j0 = (ee < 4) ? (8 * g + 2 * ee) : (32 + 8 * g + 2 * (ee - 4));
    w10u[ee] = pkrtz_u(0.5f * W1p[j0], 0.5f * W1p[j0 + 1]);
  }
  // A-frags = 0.5*W2^T (f16). tile t = out-hidden [16t,16t+16); A-row = col;
  // k element e at group g -> in-hidden kt*32 + 8g + e.
  HU afr[4][2];
#pragma unroll
  for (int t = 0; t < 4; ++t)
#pragma unroll
    for (int kt = 0; kt < 2; ++kt)
#pragma unroll
      for (int ee = 0; ee < 4; ++ee) {
        int k0 = kt * 32 + 8 * g + 2 * ee;
        afr[t][kt].u[ee] = pkrtz_u(0.5f * W2p[(k0)     * 64 + 16 * t + col],
                                   0.5f * W2p[(k0 + 1) * 64 + 16 * t + col]);
      }
  // D-side: lane holds out-hidden j = 16t + 4g + r. Bias (x0.5) as MFMA C-init.
  f32x4 cinit[4];
  unsigned w3u[8];
#pragma unroll
  for (int t = 0; t < 4; ++t) {
    int jb = 16 * t + 4 * g;
#pragma unroll
    for (int r = 0; r < 4; ++r) cinit[t][r] = 0.5f * b2p[jb + r];
    w3u[2 * t]     = pkrtz_u(W3p[jb],     W3p[jb + 1]);
    w3u[2 * t + 1] = pkrtz_u(W3p[jb + 2], W3p[jb + 3]);
  }
  const float b3v = b3p[0];

  // DP coefficients (h pre-multiplied)
  const float h   = 0.0025f;
  const float c21 = h * (1.0f / 5.0f);
  const float c31 = h * (3.0f / 40.0f),      c32 = h * (9.0f / 40.0f);
  const float c41 = h * (44.0f / 45.0f),     c42 = -h * (56.0f / 15.0f),    c43 = h * (32.0f / 9.0f);
  const float c51 = h * (19372.0f / 6561.0f), c52 = -h * (25360.0f / 2187.0f),
              c53 = h * (64448.0f / 6561.0f), c54 = -h * (212.0f / 729.0f);
  const float c61 = h * (9017.0f / 3168.0f),  c62 = -h * (355.0f / 33.0f),
              c63 = h * (46732.0f / 5247.0f), c64 = h * (49.0f / 176.0f),   c65 = -h * (5103.0f / 18656.0f);
  const float d1 = h * (35.0f / 384.0f), d3 = h * (500.0f / 1113.0f), d4 = h * (125.0f / 192.0f),
              d5 = -h * (2187.0f / 6784.0f), d6 = h * (11.0f / 84.0f);

#pragma unroll 1
  for (int job = wid; job < NBATCH / 2; job += nw) {
    const int pA = job * 32 + col;       // batch 2*job
    const int pB = pA + 16;              // batch 2*job+1
    float xA = sigmap[3 * pA + 0], xB = sigmap[3 * pB + 0];
    const float uA = sigmap[3 * pA + 1], uB = sigmap[3 * pB + 1];
    const float wdA = sigmap[3 * pA + 2], wdB = sigmap[3 * pB + 2];

    unsigned cvuA[8], cvuB[8];
#pragma unroll
    for (int ee = 0; ee < 8; ++ee) {
      int j0 = (ee < 4) ? (8 * g + 2 * ee) : (32 + 8 * g + 2 * (ee - 4));
      float wa = W1p[64 + j0], wb = W1p[64 + j0 + 1];
      float ba = b1p[j0], bb = b1p[j0 + 1];
      cvuA[ee] = pkrtz_u(0.5f * fmaf(uA, wa, ba), 0.5f * fmaf(uA, wb, bb));
      cvuB[ee] = pkrtz_u(0.5f * fmaf(uB, wa, ba), 0.5f * fmaf(uB, wb, bb));
    }

    // fused two-chain RHS: both batches' streams interleaved for ILP
    auto rhs2 = [&](float xiA, float xiB, float& oA, float& oB) {
      unsigned xhA = pkrtz_u(xiA, xiA), xhB = pkrtz_u(xiB, xiB);
      HU b0A, b1A, b0B, b1B;
#pragma unroll
      for (int ee = 0; ee < 4; ++ee) {
        b0A.u[ee] = tanh6(pk_fma_vvv(xhA, w10u[ee],     cvuA[ee]),     c2v);
        b0B.u[ee] = tanh6(pk_fma_vvv(xhB, w10u[ee],     cvuB[ee]),     c2v);
        b1A.u[ee] = tanh6(pk_fma_vvv(xhA, w10u[ee + 4], cvuA[ee + 4]), c2v);
        b1B.u[ee] = tanh6(pk_fma_vvv(xhB, w10u[ee + 4], cvuB[ee + 4]), c2v);
      }
      unsigned phA = 0, phB = 0;
#pragma unroll
      for (int t = 0; t < 4; ++t) {
        f32x4 aA = cinit[t], aB = cinit[t];
        aA = __builtin_amdgcn_mfma_f32_16x16x32_f16(afr[t][0].v, b0A.v, aA, 0, 0, 0);
        aB = __builtin_amdgcn_mfma_f32_16x16x32_f16(afr[t][0].v, b0B.v, aB, 0, 0, 0);
        aA = __builtin_amdgcn_mfma_f32_16x16x32_f16(afr[t][1].v, b1A.v, aA, 0, 0, 0);
        aB = __builtin_amdgcn_mfma_f32_16x16x32_f16(afr[t][1].v, b1B.v, aB, 0, 0, 0);
        unsigned t0A = tanh6(pkrtz_u(aA[0], aA[1]), c2v);
        unsigned t0B = tanh6(pkrtz_u(aB[0], aB[1]), c2v);
        unsigned t1A = tanh6(pkrtz_u(aA[2], aA[3]), c2v);
        unsigned t1B = tanh6(pkrtz_u(aB[2], aB[3]), c2v);
        phA = pk_fma_vvv(t0A, w3u[2 * t],     phA);
        phB = pk_fma_vvv(t0B, w3u[2 * t],     phB);
        phA = pk_fma_vvv(t1A, w3u[2 * t + 1], phA);
        phB = pk_fma_vvv(t1B, w3u[2 * t + 1], phB);
      }
      h2 hA = h_of(phA), hB = h_of(phB);
      float sA = (float)hA[0] + (float)hA[1];
      float sB = (float)hB[0] + (float)hB[1];
      sA += __shfl_xor(sA, 16, 64);
      sB += __shfl_xor(sB, 16, 64);
      sA += __shfl_xor(sA, 32, 64);
      sB += __shfl_xor(sB, 32, 64);
      oA = sA + b3v;
      oB = sB + b3v;
    };

#pragma unroll 1
    for (int step = 0; step < 4; ++step) {
      float k1A, k1B, k2A, k2B, k3A, k3B, k4A, k4B, k5A, k5B, k6A, k6B;
      rhs2(xA, xB, k1A, k1B);
      rhs2(fmaf(c21, k1A, xA), fmaf(c21, k1B, xB), k2A, k2B);
      rhs2(fmaf(c32, k2A, fmaf(c31, k1A, xA)),
           fmaf(c32, k2B, fmaf(c31, k1B, xB)), k3A, k3B);
      rhs2(fmaf(c43, k3A, fmaf(c42, k2A, fmaf(c41, k1A, xA))),
           fmaf(c43, k3B, fmaf(c42, k2B, fmaf(c41, k1B, xB))), k4A, k4B);
      rhs2(fmaf(c54, k4A, fmaf(c53, k3A, fmaf(c52, k2A, fmaf(c51, k1A, xA)))),
           fmaf(c54, k4B, fmaf(c53, k3B, fmaf(c52, k2B, fmaf(c51, k1B, xB)))),
           k5A, k5B);
      rhs2(fmaf(c65, k5A, fmaf(c64, k4A, fmaf(c63, k3A, fmaf(c62, k2A, fmaf(c61, k1A, xA))))),
           fmaf(c65, k5B, fmaf(c64, k4B, fmaf(c63, k3B, fmaf(c62, k2B, fmaf(c61, k1B, xB))))),
           k6A, k6B);
      xA = fmaf(d6, k6A, fmaf(d5, k5A, fmaf(d4, k4A, fmaf(d3, k3A, fmaf(d1, k1A, xA)))));
      xB = fmaf(d6, k6B, fmaf(d5, k5B, fmaf(d4, k4B, fmaf(d3, k3B, fmaf(d1, k1B, xB)))));
    }

    xA = fmaf(0.01f, wdA, xA);  // diffusion kick: sqrt(2*0.5*sigma^2*dt)=0.01
    xB = fmaf(0.01f, wdB, xB);

    if (lane < 16) {  // one replica writes per batch
      atomicAdd(&outp[pA / 5], Wpp[pA] * xA);
      atomicAdd(&outp[pB / 5], Wpp[pB] * xB);
    }
  }
}

extern "C" void kernel_launch(void* const* d_in, const int* in_sizes, int n_in,
                              void* d_out, int out_size, void* d_ws, size_t ws_size,
                              hipStream_t stream) {
  const float* sigmap = (const float*)d_in[0];
  const float* Wpp    = (const float*)d_in[1];
  const float* W1p    = (const float*)d_in[2];
  const float* b1p    = (const float*)d_in[3];
  const float* W2p    = (const float*)d_in[4];
  const float* b2p    = (const float*)d_in[5];
  const float* W3p    = (const float*)d_in[6];
  const float* b3p    = (const float*)d_in[7];
  float* outp = (float*)d_out;

  (void)hipMemsetAsync(outp, 0, (size_t)out_size * sizeof(float), stream);
  ode_mfma_kernel<<<2560, 256, 0, stream>>>(sigmap, Wpp, W1p, b1p, W2p, b2p,
                                            W3p, b3p, outp);
  (void)d_ws; (void)ws_size; (void)n_in; (void)in_sizes;
}